// Round 7
// baseline (65.895 us; speedup 1.0000x reference)
//
#include <hip/hip_runtime.h>
#include <math.h>

// Shapes (hard-coded per reference setup_inputs):
//   b=16, t=128, c=t-1=127, kv_dim=k=64, h=4, q_dim=256
#define Bdim 16
#define Tdim 128
#define Cdim 127
#define Hdim 4
#define QD   256
#define HK   256   // h*k
#define BT   (Bdim * Tdim)
#define ITERS 4    // bt per attn block
#define NBLK  (BT / ITERS)

// ---- DPP cross-lane move (VALU pipe — avoids ds_swizzle on the LDS pipe) ----
#define DPP_XOR1        0xB1   // quad_perm [1,0,3,2]
#define DPP_XOR2        0x4E   // quad_perm [2,3,0,1]
#define DPP_HALF_MIRROR 0x141  // mirror within 8 lanes
#define DPP_MIRROR      0x140  // mirror within 16 lanes
template<int CTRL>
__device__ __forceinline__ float dpp_movf(float x) {
    return __int_as_float(__builtin_amdgcn_update_dpp(
        0, __float_as_int(x), CTRL, 0xF, 0xF, true));
}

// ---------------------------------------------------------------------------
// K1: M[i, h*64+m] = sum_j Wq[i,h*64+j] * Wk[m,h*64+j]
__global__ __launch_bounds__(256) void precompute_M(
        const float* __restrict__ Wq, const float* __restrict__ Wk,
        float* __restrict__ M) {
    __shared__ float wk_s[64][129];   // padded: 2-way banks (free)
    __shared__ float wq_s[2][128];
    int I = blockIdx.x;               // i-pair
    int H = blockIdx.y;               // head-pair
    int tid = threadIdx.x;

    #pragma unroll
    for (int it = 0; it < 8; ++it) {
        int flat = tid + it * 256;
        int m = flat >> 5, kq = flat & 31;
        float4 v = *(const float4*)(Wk + m * HK + H * 128 + kq * 4);
        wk_s[m][kq*4+0] = v.x; wk_s[m][kq*4+1] = v.y;
        wk_s[m][kq*4+2] = v.z; wk_s[m][kq*4+3] = v.w;
    }
    if (tid < 64) {
        int r = tid >> 5, kq = tid & 31;
        float4 v = *(const float4*)(Wq + (size_t)(I*2+r) * HK + H * 128 + kq * 4);
        wq_s[r][kq*4+0] = v.x; wq_s[r][kq*4+1] = v.y;
        wq_s[r][kq*4+2] = v.z; wq_s[r][kq*4+3] = v.w;
    }
    __syncthreads();

    int r = tid >> 7, hh = (tid >> 6) & 1, m = tid & 63;
    float acc = 0.f;
    #pragma unroll 8
    for (int j = 0; j < 64; ++j)
        acc = fmaf(wq_s[r][hh*64+j], wk_s[m][hh*64+j], acc);
    M[(size_t)(I*2+r) * HK + H * 128 + hh * 64 + m] = acc;
}

// ---------------------------------------------------------------------------
// K2: qk = q_x @ M, K-split into NS partial buffers (summed in attn_main).
template <int NS>
__global__ __launch_bounds__(256) void qk_gemm(
        const float* __restrict__ q_x,
        const float* __restrict__ M,
        float* __restrict__ part) {
    const int KLEN = 256 / NS;
    __shared__ __align__(16) float q_s[16][256 / NS];
    int RB = blockIdx.x;
    int S  = blockIdx.y;
    int tid = threadIdx.x;

    for (int f = tid; f < 16 * KLEN / 4; f += 256) {
        int r = f / (KLEN / 4), kq = f % (KLEN / 4);
        *(float4*)&q_s[r][kq*4] =
            *(const float4*)(q_x + (size_t)(RB*16 + r) * QD + S * KLEN + kq * 4);
    }
    __syncthreads();

    float acc[16];
    #pragma unroll
    for (int r = 0; r < 16; ++r) acc[r] = 0.f;

    for (int kk = 0; kk < KLEN / 4; ++kk) {
        int k = S * KLEN + kk * 4;
        float m0 = M[(size_t)(k+0) * HK + tid];
        float m1 = M[(size_t)(k+1) * HK + tid];
        float m2 = M[(size_t)(k+2) * HK + tid];
        float m3 = M[(size_t)(k+3) * HK + tid];
        #pragma unroll
        for (int r = 0; r < 16; ++r) {
            float4 qv = *(const float4*)&q_s[r][kk*4];
            acc[r] = fmaf(qv.x, m0, fmaf(qv.y, m1, fmaf(qv.z, m2, fmaf(qv.w, m3, acc[r]))));
        }
    }
    float* dst = part + (size_t)S * (BT*HK) + (size_t)RB * 16 * HK + tid;
    #pragma unroll
    for (int r = 0; r < 16; ++r) dst[r * HK] = acc[r];
}

// ---------------------------------------------------------------------------
// Stage one bt's X (127x64 f32 = 2032 float4) into LDS buffer via DMA.
// LDS dest linear; global source pre-swizzled: LDS[c][p] = X[c][p ^ (c&7)].
// Uniform 4 instrs/thread (l>=2032 clamped to chunk 0; row 127 masked later).
__device__ __forceinline__ void stage_x(const float4* __restrict__ Xg,
                                        float4* dst, int tid) {
    #pragma unroll
    for (int itr = 0; itr < 4; ++itr) {
        int l = tid + itr * 512;
        int c = l >> 4, p = l & 15;
        int src = (l < Cdim * 16) ? ((c << 4) + (p ^ (c & 7))) : 0;
        __builtin_amdgcn_global_load_lds(
            (const __attribute__((address_space(1))) void*)(Xg + src),
            (__attribute__((address_space(3))) void*)(dst + l), 16, 0, 0);
    }
}

// ---------------------------------------------------------------------------
// K3: persistent pipeline — ITERS bt per block, double-buffered X, counted
// vmcnt (prefetch never drained to 0 inside the loop), raw s_barrier.
// 512 thr / 8 waves; 69.7 KB LDS -> 2 blocks/CU = 16 waves/CU.
// Waves 0-3: qk staging + scores + wx.  Waves 4-7: scores + wx + epilogue
// (Wv held in 64 registers, loaded once per block).
template <int NS>
__global__ __launch_bounds__(512, 4) void attn_main(
        const float* __restrict__ kv_x,
        const float* __restrict__ qk_p,
        const float* __restrict__ Wv,
        float* __restrict__ out) {
    __shared__ __align__(16) float4 sX[2 * 2048];        // 64 KB, dbuf
    __shared__ __align__(16) float qk_s[2][HK];          // dbuf
    __shared__ __align__(16) float e_lds[128 * 5 + 4];
    __shared__ __align__(16) float4 wx4[Hdim * 16];
    __shared__ float red_max[Hdim][2];
    __shared__ float red_sum[Hdim][2];

    int blk = blockIdx.x;
    int tid = threadIdx.x;
    bool hiw = (tid >= 256);                             // wave-uniform
    int bt0 = blk * ITERS;

    // ---- Wv columns into registers (waves 4-7), reused across ITERS ----
    float wv[64];
    if (hiw) {
        int col = tid & 255;
        #pragma unroll
        for (int j = 0; j < 64; ++j) wv[j] = Wv[(size_t)j * HK + col];
    }

    // ---- prologue: DMA bt0 into buf0, then qk partial loads for bt0 ----
    stage_x((const float4*)(kv_x + (size_t)bt0 * (Cdim * 64)), sX, tid);
    __builtin_amdgcn_sched_barrier(0);
    float r[NS];
    if (!hiw) {
        #pragma unroll
        for (int s = 0; s < NS; ++s)
            r[s] = qk_p[(size_t)s * (BT*HK) + (size_t)bt0 * HK + tid];
    }

    int h    = tid >> 7;          // head (wave-uniform)
    int c    = tid & 127;         // context row for scores
    int half = (tid >> 6) & 1;
    int lane = tid & 63;
    int sw   = c & 7;

    for (int it = 0; it < ITERS; ++it) {
        int cur = it & 1;
        int bt = bt0 + it;
        bool have_nxt = (it + 1 < ITERS);

        __builtin_amdgcn_s_barrier();                    // #A: buf[nxt]+aux free
        __builtin_amdgcn_sched_barrier(0);

        // prefetch next bt's X (stays in flight across all barriers below)
        if (have_nxt)
            stage_x((const float4*)(kv_x + (size_t)(bt+1) * (Cdim * 64)),
                    sX + (cur ^ 1) * 2048, tid);
        __builtin_amdgcn_sched_barrier(0);

        if (!hiw) {
            // consuming r forces compiler vmcnt wait -> drains own DMA(cur) too
            float qsum = 0.f;
            #pragma unroll
            for (int s = 0; s < NS; ++s) qsum += r[s];
            if (have_nxt) {
                #pragma unroll
                for (int s = 0; s < NS; ++s)
                    r[s] = qk_p[(size_t)s * (BT*HK) + (size_t)(bt+1) * HK + tid];
            }
            qk_s[cur][tid] = qsum;
            asm volatile("s_waitcnt lgkmcnt(0)" ::: "memory");
        } else {
            // no data dependency drains these waves' DMA(cur): do it manually,
            // leaving the 4 DMA(nxt) in flight
            if (have_nxt) asm volatile("s_waitcnt vmcnt(4)" ::: "memory");
            else          asm volatile("s_waitcnt vmcnt(0)" ::: "memory");
        }
        __builtin_amdgcn_s_barrier();                    // #B: X(cur)+qk ready
        __builtin_amdgcn_sched_barrier(0);

        // ---- scores ----
        float s;
        {
            const float4* qrow = (const float4*)(qk_s[cur] + h * 64);
            const float4* xrow = sX + cur * 2048 + c * 16;
            float acc = 0.f;
            #pragma unroll
            for (int p = 0; p < 16; ++p) {
                float4 qv = qrow[p];                     // broadcast
                float4 x4 = xrow[p ^ sw];                // 8 addrs x 8 groups
                acc = fmaf(qv.x, x4.x, fmaf(qv.y, x4.y, fmaf(qv.z, x4.z, fmaf(qv.w, x4.w, acc))));
            }
            s = (c < Cdim) ? acc * 0.125f : -INFINITY;   // row 127 = garbage
        }

        // ---- softmax max (DPP + 2 shfl), cross-wave via LDS ----
        float mx = s;
        mx = fmaxf(mx, dpp_movf<DPP_XOR1>(mx));
        mx = fmaxf(mx, dpp_movf<DPP_XOR2>(mx));
        mx = fmaxf(mx, dpp_movf<DPP_HALF_MIRROR>(mx));
        mx = fmaxf(mx, dpp_movf<DPP_MIRROR>(mx));
        mx = fmaxf(mx, __shfl_xor(mx, 16, 64));
        mx = fmaxf(mx, __shfl_xor(mx, 32, 64));
        if (lane == 0) red_max[h][half] = mx;
        asm volatile("s_waitcnt lgkmcnt(0)" ::: "memory");
        __builtin_amdgcn_s_barrier();                    // #C
        __builtin_amdgcn_sched_barrier(0);

        float gm = fmaxf(red_max[h][0], red_max[h][1]);
        float e = __expf(s - gm);                        // c==127 -> 0
        e_lds[c * 5 + h] = e;
        float sm = e;
        sm += dpp_movf<DPP_XOR1>(sm);
        sm += dpp_movf<DPP_XOR2>(sm);
        sm += dpp_movf<DPP_HALF_MIRROR>(sm);
        sm += dpp_movf<DPP_MIRROR>(sm);
        sm += __shfl_xor(sm, 16, 64);
        sm += __shfl_xor(sm, 32, 64);
        if (lane == 0) red_sum[h][half] = sm;
        asm volatile("s_waitcnt lgkmcnt(0)" ::: "memory");
        __builtin_amdgcn_s_barrier();                    // #D
        __builtin_amdgcn_sched_barrier(0);

        // ---- wx[h][jc] = sum_c e[h,c]*X[c,chunk jc]; thread=(h,jc,csub) ----
        {
            int jc = (tid >> 3) & 15;
            int cs = tid & 7;
            const float4* xbase = sX + cur * 2048 + cs * 16 + (jc ^ cs);
            const float* ebase  = e_lds + cs * 5 + h;
            float4 a = {0.f, 0.f, 0.f, 0.f};
            #pragma unroll
            for (int m = 0; m < 16; ++m) {
                float4 x4 = xbase[m * 128];              // row cs+8m
                float ev  = ebase[m * 40];               // 8 banks, no conflict
                a.x = fmaf(ev, x4.x, a.x);
                a.y = fmaf(ev, x4.y, a.y);
                a.z = fmaf(ev, x4.z, a.z);
                a.w = fmaf(ev, x4.w, a.w);
            }
            a.x += dpp_movf<DPP_XOR1>(a.x); a.y += dpp_movf<DPP_XOR1>(a.y);
            a.z += dpp_movf<DPP_XOR1>(a.z); a.w += dpp_movf<DPP_XOR1>(a.w);
            a.x += dpp_movf<DPP_XOR2>(a.x); a.y += dpp_movf<DPP_XOR2>(a.y);
            a.z += dpp_movf<DPP_XOR2>(a.z); a.w += dpp_movf<DPP_XOR2>(a.w);
            a.x += dpp_movf<DPP_HALF_MIRROR>(a.x); a.y += dpp_movf<DPP_HALF_MIRROR>(a.y);
            a.z += dpp_movf<DPP_HALF_MIRROR>(a.z); a.w += dpp_movf<DPP_HALF_MIRROR>(a.w);
            if (cs == 0) wx4[h * 16 + jc] = a;
        }
        asm volatile("s_waitcnt lgkmcnt(0)" ::: "memory");
        __builtin_amdgcn_s_barrier();                    // #E
        __builtin_amdgcn_sched_barrier(0);

        // ---- epilogue on waves 4-7 (Wv in registers) ----
        if (hiw) {
            int col = tid & 255;
            int hh = col >> 6;
            float inv = 1.f / (red_sum[hh][0] + red_sum[hh][1]);
            float acc = 0.f;
            #pragma unroll
            for (int jc = 0; jc < 16; ++jc) {
                float4 w4 = wx4[hh * 16 + jc];           // b128 broadcast
                acc = fmaf(w4.x, wv[jc*4+0],
                      fmaf(w4.y, wv[jc*4+1],
                      fmaf(w4.z, wv[jc*4+2],
                      fmaf(w4.w, wv[jc*4+3], acc))));
            }
            out[(size_t)bt * HK + col] = acc * inv;
        }
    }
}

extern "C" void kernel_launch(void* const* d_in, const int* in_sizes, int n_in,
                              void* d_out, int out_size, void* d_ws, size_t ws_size,
                              hipStream_t stream) {
    const float* q_x  = (const float*)d_in[0];   // [16,128,256]
    const float* kv_x = (const float*)d_in[1];   // [16,128,127,64]
    const float* Wq   = (const float*)d_in[2];   // [256,256]
    const float* Wk   = (const float*)d_in[3];   // [64,256]
    const float* Wv   = (const float*)d_in[4];   // [64,256]
    float* out = (float*)d_out;                  // [16,128,256] f32

    float* M     = (float*)d_ws;                 // 256*256 floats
    float* parts = M + 256 * 256;                // NS * 2048*256 floats

    size_t need4 = (size_t)(256*256 + 4 * BT*HK) * sizeof(float);
    int nsplit = (ws_size >= need4) ? 4 : 1;

    precompute_M<<<dim3(128, 2), 256, 0, stream>>>(Wq, Wk, M);
    if (nsplit == 4) {
        qk_gemm<4><<<dim3(128, 4), 256, 0, stream>>>(q_x, M, parts);
        attn_main<4><<<NBLK, 512, 0, stream>>>(kv_x, parts, Wv, out);
    } else {
        qk_gemm<1><<<dim3(128, 1), 256, 0, stream>>>(q_x, M, parts);
        attn_main<1><<<NBLK, 512, 0, stream>>>(kv_x, parts, Wv, out);
    }
}

// Round 8
// 42.462 us; speedup vs baseline: 1.5519x; 1.5519x over previous
//
#include <hip/hip_runtime.h>
#include <math.h>

// Shapes (hard-coded per reference setup_inputs):
//   b=16, t=128, c=t-1=127, kv_dim=k=64, h=4, q_dim=256
#define Bdim 16
#define Tdim 128
#define Cdim 127
#define Hdim 4
#define QD   256
#define HK   256   // h*k
#define BT   (Bdim * Tdim)

// ---- DPP cross-lane move (VALU pipe — keeps LDS pipe free) ----
#define DPP_XOR1        0xB1   // quad_perm [1,0,3,2]
#define DPP_XOR2        0x4E   // quad_perm [2,3,0,1]
#define DPP_HALF_MIRROR 0x141  // mirror within 8 lanes (lane^7)
#define DPP_MIRROR      0x140  // mirror within 16 lanes (lane^15)
template<int CTRL>
__device__ __forceinline__ float dpp_movf(float x) {
    return __int_as_float(__builtin_amdgcn_update_dpp(
        0, __float_as_int(x), CTRL, 0xF, 0xF, true));
}
// quad butterfly sum (lane bits 0-1)
__device__ __forceinline__ float quad_sum(float v) {
    v += dpp_movf<DPP_XOR1>(v);
    v += dpp_movf<DPP_XOR2>(v);
    return v;
}
// reduce over the 16 rows of a wave (lane bits 2-5), assumes bits0-1 uniform
__device__ __forceinline__ float rows_max(float v) {
    v = fmaxf(v, dpp_movf<DPP_HALF_MIRROR>(v));
    v = fmaxf(v, dpp_movf<DPP_MIRROR>(v));
    v = fmaxf(v, __shfl_xor(v, 16, 64));
    v = fmaxf(v, __shfl_xor(v, 32, 64));
    return v;
}
__device__ __forceinline__ float rows_sum(float v) {
    v += dpp_movf<DPP_HALF_MIRROR>(v);
    v += dpp_movf<DPP_MIRROR>(v);
    v += __shfl_xor(v, 16, 64);
    v += __shfl_xor(v, 32, 64);
    return v;
}
// reduce over cs (bits0-2) + mq (bits3-4)
__device__ __forceinline__ float wx_red(float v) {
    v += dpp_movf<DPP_XOR1>(v);
    v += dpp_movf<DPP_XOR2>(v);
    v += dpp_movf<DPP_HALF_MIRROR>(v);
    v += dpp_movf<DPP_MIRROR>(v);
    v += __shfl_xor(v, 16, 64);
    return v;
}

// ---------------------------------------------------------------------------
// K1: M[i, h*64+m] = sum_j Wq[i,h*64+j] * Wk[m,h*64+j]
__global__ __launch_bounds__(256) void precompute_M(
        const float* __restrict__ Wq, const float* __restrict__ Wk,
        float* __restrict__ M) {
    __shared__ float wk_s[64][129];   // padded: 2-way banks (free)
    __shared__ float wq_s[2][128];
    int I = blockIdx.x;               // i-pair
    int H = blockIdx.y;               // head-pair
    int tid = threadIdx.x;

    #pragma unroll
    for (int it = 0; it < 8; ++it) {
        int flat = tid + it * 256;
        int m = flat >> 5, kq = flat & 31;
        float4 v = *(const float4*)(Wk + m * HK + H * 128 + kq * 4);
        wk_s[m][kq*4+0] = v.x; wk_s[m][kq*4+1] = v.y;
        wk_s[m][kq*4+2] = v.z; wk_s[m][kq*4+3] = v.w;
    }
    if (tid < 64) {
        int r = tid >> 5, kq = tid & 31;
        float4 v = *(const float4*)(Wq + (size_t)(I*2+r) * HK + H * 128 + kq * 4);
        wq_s[r][kq*4+0] = v.x; wq_s[r][kq*4+1] = v.y;
        wq_s[r][kq*4+2] = v.z; wq_s[r][kq*4+3] = v.w;
    }
    __syncthreads();

    int r = tid >> 7, hh = (tid >> 6) & 1, m = tid & 63;
    float acc = 0.f;
    #pragma unroll 8
    for (int j = 0; j < 64; ++j)
        acc = fmaf(wq_s[r][hh*64+j], wk_s[m][hh*64+j], acc);
    M[(size_t)(I*2+r) * HK + H * 128 + hh * 64 + m] = acc;
}

// ---------------------------------------------------------------------------
// K2: qk = q_x @ M, K-split into NS partial buffers (summed in attn_main).
template <int NS>
__global__ __launch_bounds__(256) void qk_gemm(
        const float* __restrict__ q_x,
        const float* __restrict__ M,
        float* __restrict__ part) {
    const int KLEN = 256 / NS;
    __shared__ __align__(16) float q_s[16][256 / NS];
    int RB = blockIdx.x;
    int S  = blockIdx.y;
    int tid = threadIdx.x;

    for (int f = tid; f < 16 * KLEN / 4; f += 256) {
        int r = f / (KLEN / 4), kq = f % (KLEN / 4);
        *(float4*)&q_s[r][kq*4] =
            *(const float4*)(q_x + (size_t)(RB*16 + r) * QD + S * KLEN + kq * 4);
    }
    __syncthreads();

    float acc[16];
    #pragma unroll
    for (int r = 0; r < 16; ++r) acc[r] = 0.f;

    for (int kk = 0; kk < KLEN / 4; ++kk) {
        int k = S * KLEN + kk * 4;
        float m0 = M[(size_t)(k+0) * HK + tid];
        float m1 = M[(size_t)(k+1) * HK + tid];
        float m2 = M[(size_t)(k+2) * HK + tid];
        float m3 = M[(size_t)(k+3) * HK + tid];
        #pragma unroll
        for (int r = 0; r < 16; ++r) {
            float4 qv = *(const float4*)&q_s[r][kk*4];
            acc[r] = fmaf(qv.x, m0, fmaf(qv.y, m1, fmaf(qv.z, m2, fmaf(qv.w, m3, acc[r]))));
        }
    }
    float* dst = part + (size_t)S * (BT*HK) + (size_t)RB * 16 * HK + tid;
    #pragma unroll
    for (int r = 0; r < 16; ++r) dst[r * HK] = acc[r];
}

// ---------------------------------------------------------------------------
// K3: per (b,t): scores -> softmax -> wx -> V-proj, ALL 4 HEADS FUSED per
// X-pass (X read 2x/block from LDS instead of 8x).  512 thr / 8 waves.
// X row-major float4 chunks, XOR slot swizzle phys = log ^ (c&7), DMA-staged.
template <int NS>
__global__ __launch_bounds__(512, 6) void attn_main(
        const float* __restrict__ kv_x,
        const float* __restrict__ qk_p,
        const float* __restrict__ Wv,
        float* __restrict__ out) {
    __shared__ __align__(16) float4 sX4[128 * 16];   // 32 KB; row 127 zeroed
    __shared__ __align__(16) float qk_s[HK];
    __shared__ __align__(16) float4 e4[128];         // e per (c, 4 heads)
    __shared__ __align__(16) float4 wx4[Hdim * 16];  // wx as float4 chunks
    __shared__ __align__(16) float4 redm[8];         // per-wave max (4 heads)
    __shared__ __align__(16) float4 reds[8];         // per-wave sum (4 heads)

    int bt  = blockIdx.x;
    int tid = threadIdx.x;

    // ---- stage X via DMA (linear LDS dest, pre-swizzled global source) ----
    const float4* Xg = (const float4*)(kv_x + (size_t)bt * (Cdim * 64));
    #pragma unroll
    for (int it = 0; it < 4; ++it) {
        int l = tid + it * 512;
        if (l < Cdim * 16) {
            int c = l >> 4, p = l & 15;
            __builtin_amdgcn_global_load_lds(
                (const __attribute__((address_space(1))) void*)(Xg + (c << 4) + (p ^ (c & 7))),
                (__attribute__((address_space(3))) void*)(sX4 + l), 16, 0, 0);
        }
    }
    if (tid >= 256 && tid < 320)
        ((float*)sX4)[Cdim * 64 + (tid - 256)] = 0.f;     // zero pad row 127
    if (tid < 256) {
        float q = 0.f;
        #pragma unroll
        for (int s = 0; s < NS; ++s)
            q += qk_p[(size_t)s * (BT*HK) + (size_t)bt * HK + tid];
        qk_s[tid] = q;
    }
    __syncthreads();                                      // B1

    int lane = tid & 63;
    int wave = tid >> 6;
    int c  = tid >> 2;            // 0..127 : row (lane bits 2-5 + wave)
    int qp = tid & 3;             // quarter of the row
    int sw = c & 7;

    // ---- scores, all 4 heads in one X pass ----
    // thread reads 4 X-chunks once; dots vs 4 heads' qk (2-way multicast).
    float s0, s1, s2, s3;
    {
        const float4* xrow = sX4 + c * 16;
        float4 x0 = xrow[(qp*4 + 0) ^ sw];   // 8 addrs x 8 groups (struct-min)
        float4 x1 = xrow[(qp*4 + 1) ^ sw];
        float4 x2 = xrow[(qp*4 + 2) ^ sw];
        float4 x3 = xrow[(qp*4 + 3) ^ sw];
        const float4* qk4 = (const float4*)qk_s;
        float a0 = 0.f, a1 = 0.f, a2 = 0.f, a3 = 0.f;
        #pragma unroll
        for (int i = 0; i < 4; ++i) {
            float4 xi = (i == 0) ? x0 : (i == 1) ? x1 : (i == 2) ? x2 : x3;
            float4 q0 = qk4[0*16 + qp*4 + i];   // 4 addrs, 2/bank-group: ~free
            float4 q1 = qk4[1*16 + qp*4 + i];
            float4 q2 = qk4[2*16 + qp*4 + i];
            float4 q3 = qk4[3*16 + qp*4 + i];
            a0 = fmaf(q0.x, xi.x, fmaf(q0.y, xi.y, fmaf(q0.z, xi.z, fmaf(q0.w, xi.w, a0))));
            a1 = fmaf(q1.x, xi.x, fmaf(q1.y, xi.y, fmaf(q1.z, xi.z, fmaf(q1.w, xi.w, a1))));
            a2 = fmaf(q2.x, xi.x, fmaf(q2.y, xi.y, fmaf(q2.z, xi.z, fmaf(q2.w, xi.w, a2))));
            a3 = fmaf(q3.x, xi.x, fmaf(q3.y, xi.y, fmaf(q3.z, xi.z, fmaf(q3.w, xi.w, a3))));
        }
        // quad butterfly over qp -> all 4 lanes hold the full row-dot
        a0 = quad_sum(a0); a1 = quad_sum(a1); a2 = quad_sum(a2); a3 = quad_sum(a3);
        bool valid = (c < Cdim);
        s0 = valid ? a0 * 0.125f : -INFINITY;   // 1/sqrt(64); row 127 pad
        s1 = valid ? a1 * 0.125f : -INFINITY;
        s2 = valid ? a2 * 0.125f : -INFINITY;
        s3 = valid ? a3 * 0.125f : -INFINITY;
    }

    // ---- softmax max: per-wave row reduce, cross-wave via redm ----
    float m0 = rows_max(s0), m1 = rows_max(s1), m2 = rows_max(s2), m3 = rows_max(s3);
    if (lane == 0) redm[wave] = make_float4(m0, m1, m2, m3);
    __syncthreads();                                      // B2
    float4 gm = redm[0];
    #pragma unroll
    for (int w = 1; w < 8; ++w) {
        float4 r = redm[w];
        gm.x = fmaxf(gm.x, r.x); gm.y = fmaxf(gm.y, r.y);
        gm.z = fmaxf(gm.z, r.z); gm.w = fmaxf(gm.w, r.w);
    }
    float e0 = __expf(s0 - gm.x);            // c==127 -> 0
    float e1 = __expf(s1 - gm.y);
    float e2 = __expf(s2 - gm.z);
    float e3 = __expf(s3 - gm.w);
    if (qp == 0) e4[c] = make_float4(e0, e1, e2, e3);     // 2 addrs/group: free
    float t0 = rows_sum(e0), t1 = rows_sum(e1), t2 = rows_sum(e2), t3 = rows_sum(e3);
    if (lane == 0) reds[wave] = make_float4(t0, t1, t2, t3);
    __syncthreads();                                      // B3 (e4+reds ready)

    // ---- wx[h][jc] = sum_c e[h,c]*X[c,chunk jc], 4 heads per X pass ----
    // thread = (jc = tid>>5, mq = bits3-4, cs = bits0-2); c = cs + 8m.
    {
        int jc = tid >> 5;
        int mq = (lane >> 3) & 3;
        int cs = lane & 7;
        float4 A0 = {0,0,0,0}, A1 = {0,0,0,0}, A2 = {0,0,0,0}, A3 = {0,0,0,0};
        #pragma unroll
        for (int mm = 0; mm < 4; ++mm) {
            int cc = cs + 8 * (mq * 4 + mm);
            float4 x4 = sX4[cc * 16 + (jc ^ cs)];   // phys = log ^ (c&7)
            float4 ee = e4[cc];                     // b128, 4 phases
            A0.x = fmaf(ee.x, x4.x, A0.x); A0.y = fmaf(ee.x, x4.y, A0.y);
            A0.z = fmaf(ee.x, x4.z, A0.z); A0.w = fmaf(ee.x, x4.w, A0.w);
            A1.x = fmaf(ee.y, x4.x, A1.x); A1.y = fmaf(ee.y, x4.y, A1.y);
            A1.z = fmaf(ee.y, x4.z, A1.z); A1.w = fmaf(ee.y, x4.w, A1.w);
            A2.x = fmaf(ee.z, x4.x, A2.x); A2.y = fmaf(ee.z, x4.y, A2.y);
            A2.z = fmaf(ee.z, x4.z, A2.z); A2.w = fmaf(ee.z, x4.w, A2.w);
            A3.x = fmaf(ee.w, x4.x, A3.x); A3.y = fmaf(ee.w, x4.y, A3.y);
            A3.z = fmaf(ee.w, x4.z, A3.z); A3.w = fmaf(ee.w, x4.w, A3.w);
        }
        // reduce over cs (bits0-2) + mq (bits3-4) on the VALU
        A0.x = wx_red(A0.x); A0.y = wx_red(A0.y); A0.z = wx_red(A0.z); A0.w = wx_red(A0.w);
        A1.x = wx_red(A1.x); A1.y = wx_red(A1.y); A1.z = wx_red(A1.z); A1.w = wx_red(A1.w);
        A2.x = wx_red(A2.x); A2.y = wx_red(A2.y); A2.z = wx_red(A2.z); A2.w = wx_red(A2.w);
        A3.x = wx_red(A3.x); A3.y = wx_red(A3.y); A3.z = wx_red(A3.z); A3.w = wx_red(A3.w);
        if ((lane & 31) == 0) {                  // lanes 0 and 32 (their jc)
            wx4[0 * 16 + jc] = A0;
            wx4[1 * 16 + jc] = A1;
            wx4[2 * 16 + jc] = A2;
            wx4[3 * 16 + jc] = A3;
        }
    }
    __syncthreads();                                      // B4

    // ---- out[h,k] = inv * sum_j wx[h,j] * Wv[j, h*64+k]; tid<256 ----
    if (tid < 256) {
        int hh = tid >> 6, k = tid & 63;
        float4 sums = reds[0];
        #pragma unroll
        for (int w = 1; w < 8; ++w) {
            float4 r = reds[w];
            sums.x += r.x; sums.y += r.y; sums.z += r.z; sums.w += r.w;
        }
        float denom = (hh == 0) ? sums.x : (hh == 1) ? sums.y
                    : (hh == 2) ? sums.z : sums.w;        // wave-uniform select
        float inv = 1.f / denom;
        const float* wvcol = Wv + hh * 64 + k;
        float acc = 0.f;
        #pragma unroll 4
        for (int jc = 0; jc < 16; ++jc) {
            float4 w4 = wx4[hh * 16 + jc];       // b128 broadcast
            acc = fmaf(w4.x, wvcol[(size_t)(jc*4+0) * HK],
                  fmaf(w4.y, wvcol[(size_t)(jc*4+1) * HK],
                  fmaf(w4.z, wvcol[(size_t)(jc*4+2) * HK],
                  fmaf(w4.w, wvcol[(size_t)(jc*4+3) * HK], acc))));
        }
        out[(size_t)bt * HK + tid] = acc * inv;
    }
}

extern "C" void kernel_launch(void* const* d_in, const int* in_sizes, int n_in,
                              void* d_out, int out_size, void* d_ws, size_t ws_size,
                              hipStream_t stream) {
    const float* q_x  = (const float*)d_in[0];   // [16,128,256]
    const float* kv_x = (const float*)d_in[1];   // [16,128,127,64]
    const float* Wq   = (const float*)d_in[2];   // [256,256]
    const float* Wk   = (const float*)d_in[3];   // [64,256]
    const float* Wv   = (const float*)d_in[4];   // [64,256]
    float* out = (float*)d_out;                  // [16,128,256] f32

    float* M     = (float*)d_ws;                 // 256*256 floats
    float* parts = M + 256 * 256;                // NS * 2048*256 floats

    size_t need4 = (size_t)(256*256 + 4 * BT*HK) * sizeof(float);
    int nsplit = (ws_size >= need4) ? 4 : 1;

    precompute_M<<<dim3(128, 2), 256, 0, stream>>>(Wq, Wk, M);
    if (nsplit == 4) {
        qk_gemm<4><<<dim3(128, 4), 256, 0, stream>>>(q_x, M, parts);
        attn_main<4><<<BT, 512, 0, stream>>>(kv_x, parts, Wv, out);
    } else {
        qk_gemm<1><<<dim3(128, 1), 256, 0, stream>>>(q_x, M, parts);
        attn_main<1><<<BT, 512, 0, stream>>>(kv_x, parts, Wv, out);
    }
}